// Round 11
// baseline (105.669 us; speedup 1.0000x reference)
//
#include <hip/hip_runtime.h>
#include <math.h>

#define BB 16
#define PP 65536
#define GG 16
#define NBIN 2048
#define ITEMS 4
#define ITIOU 2
#define SLOT 64
#define ZBYTES 282176
#define ZQUADS (ZBYTES/16)

typedef unsigned int u32;
typedef unsigned long long u64;

__device__ __forceinline__ float splus(float x){
    float t = __builtin_amdgcn_exp2f(fabsf(x) * -1.4426950408889634f);
    float l = __builtin_amdgcn_logf(1.0f + t);
    return __builtin_fmaf(l, 0.6931471805599453f, fmaxf(x, 0.f));
}

// DPP row-rotate (within 16-lane row) — VALU op, keeps the argmax reduction
// off the DS pipe (shfl_xor = ds_bpermute dep-chains were the round-3 stall).
#define DPP_ROR(v, CTRL) ((u32)__builtin_amdgcn_update_dpp(0, (int)(v), (CTRL), 0xF, 0xF, true))
#define ARG_LEVEL(CTRL) { \
    u32 oiu = DPP_ROR(__float_as_uint(bi_), CTRL); \
    u32 odu = DPP_ROR(__float_as_uint(bd_), CTRL); \
    u32 opu = DPP_ROR(bp_, CTRL); \
    float oi = __uint_as_float(oiu), od = __uint_as_float(odu); \
    float a1 = oi*bd_, a2 = bi_*od; \
    bool take = (a1 > a2) || ((a1 == a2) && (opu > bp_)); \
    if (take){ bi_=oi; bd_=od; bp_=opu; } }

// ---- tiny workspace zero (rocclr small-fill is a ~41us latency-bound kernel) ----
__global__ __launch_bounds__(256) void k_zero(uint4* __restrict__ p, u32 n16){
    u32 i = blockIdx.x*256u + threadIdx.x;
    if (i < n16) p[i] = make_uint4(0u,0u,0u,0u);
}

// ---- k_hist: streaming phase split out of k_mb. conf -> softplus bits ->
// sbits store + per-block LDS histogram -> Hall/Sall flush. ----
__global__ __launch_bounds__(256) void k_hist(const float* __restrict__ conf,
                                              u32* __restrict__ sbits,
                                              u32* __restrict__ Hall, float* __restrict__ Sall){
    const int b = blockIdx.x >> 6;
    const int chunk = blockIdx.x & 63;
    const int tid = threadIdx.x;
    __shared__ u32 hc[NBIN];
    __shared__ float hs[NBIN];
    for (int i=tid;i<NBIN;i+=256){ hc[i]=0u; hs[i]=0.f; }
    __syncthreads();
#pragma unroll
    for (int i=0;i<ITEMS;++i){
        int p = chunk*1024 + i*256 + tid;
        size_t off = (size_t)b*PP + p;
        float s = splus(conf[off]);
        u32 bits = __float_as_uint(s);
        sbits[off] = bits;
        u32 cb = bits >> 20;
        atomicAdd(&hc[cb], 1u);
        atomicAdd(&hs[cb], s);
    }
    __syncthreads();
    for (int i=tid;i<NBIN;i+=256){
        u32 cv = hc[i];
        if (cv){ atomicAdd(&Hall[i], cv); atomicAdd(&Sall[i], hs[i]); }
    }
}

// ---- k_iou: latency-bound phase at 2x occupancy. 2048 blocks x 2 priors/
// thread; ~1KB LDS (NBIN hist removed -> LDS no longer caps blocks/CU). ----
__global__ __launch_bounds__(256) void k_iou(const float* __restrict__ conf,
                                             const float4* __restrict__ reg,
                                             const float4* __restrict__ prior,
                                             const float4* __restrict__ gt,
                                             const u32* __restrict__ sbits,
                                             u64* __restrict__ best,
                                             unsigned short* __restrict__ mmask,
                                             u32* __restrict__ Hm, float* __restrict__ Sm,
                                             double* __restrict__ scal){
    const int b = blockIdx.x >> 7;
    const int chunk = blockIdx.x & 127;
    const int tid = threadIdx.x;
    const int lane = tid & 63, wv = tid >> 6;
    __shared__ float wbi[4][GG], wbd[4][GG];
    __shared__ u32 wbp[4][GG];
    __shared__ double wl[4], wc[4];

    const int p0 = chunk*512 + tid;
    float x[ITIOU], sp[ITIOU];
    float px0[ITIOU], py0[ITIOU], px1[ITIOU], py1[ITIOU], pa[ITIOU];
    u32 invp[ITIOU], mm[ITIOU];
#pragma unroll
    for (int i=0;i<ITIOU;++i){
        int p = p0 + i*256;
        size_t off = (size_t)b*PP + p;
        x[i] = conf[off];
        sp[i] = __uint_as_float(sbits[off]);   // exact softplus bits from k_hist
        mm[i]=0u;
        invp[i] = 0xFFFFFFFFu - (u32)p;
        float4 pb = prior[off];
        px0[i]=pb.x; py0[i]=pb.y; px1[i]=pb.z; py1[i]=pb.w;
        pa[i]=(pb.z-pb.x)*(pb.w-pb.y);
    }

    // exact: RN(inter/den) >= 0.5  <=>  inter/den >= 0.5 - 2^-27 (tie-to-even
    // midpoint rounds UP to 0.5) <=> inter >= (0.5-2^-27)*den, exact in f64.
    const double CH = 0.5 - 1.0/134217728.0;
    const int myg = lane & 15;
    float ti=0.f, td=1.f; u32 tp_=0u;   // this lane's persistent triple for g = myg
#pragma unroll
    for (int g=0; g<GG; ++g){
        float4 gb = gt[b*GG + g];
        float ga = (gb.z-gb.x)*(gb.w-gb.y);
        float bi_ = 0.f, bd_ = 1.f; u32 bp_ = 0u;   // best (inter, den, invp)
#pragma unroll
        for (int i=0;i<ITIOU;++i){
            float lx = fmaxf(px0[i], gb.x), ly = fmaxf(py0[i], gb.y);
            float rx = fminf(px1[i], gb.z), ry = fminf(py1[i], gb.w);
            float w = fmaxf(rx-lx, 0.f), h = fmaxf(ry-ly, 0.f);
            float inter = w*h;                   // boxes <= ~1.05, 100-clip is a no-op
            float den = pa[i] + ga - inter;
            bool pre = (inter >= 0.49f*den);     // conservative; no false negatives
            if (__any(pre)){
                if ((double)inter >= CH*(double)den) mm[i] |= (1u<<g);
            }
            // argmax of inter/den via cross-multiply (division-free)
            float a1 = inter*bd_, a2 = bi_*den;
            bool take = (a1 > a2) || ((a1 == a2) && (invp[i] > bp_));
            if (take){ bi_=inter; bd_=den; bp_=invp[i]; }
        }
        // 4-level VALU (DPP row_ror) reduction within 16-lane groups
        ARG_LEVEL(0x121)   // row_ror:1
        ARG_LEVEL(0x122)   // row_ror:2
        ARG_LEVEL(0x124)   // row_ror:4
        ARG_LEVEL(0x128)   // row_ror:8
        if (myg == g){ ti=bi_; td=bd_; tp_=bp_; }   // keep only own g (static idx)
    }
    // cross-group reduce (4 groups of 16) on the single kept triple: 6 DS ops/wave
#pragma unroll
    for (int off=32; off>=16; off>>=1){
        float oi = __shfl_xor(ti, off);
        float od = __shfl_xor(td, off);
        u32  op = __shfl_xor(tp_, off);
        float a1 = oi*td, a2 = ti*od;
        bool take = (a1 > a2) || ((a1 == a2) && (op > tp_));
        if (take){ ti=oi; td=od; tp_=op; }
    }
    if (lane < 16){ wbi[wv][lane]=ti; wbd[wv][lane]=td; wbp[wv][lane]=tp_; }
    __syncthreads();
    if (tid < GG){
        float fi = wbi[0][tid], fd = wbd[0][tid]; u32 fp = wbp[0][tid];
#pragma unroll
        for (int w2=1; w2<4; ++w2){
            float oi = wbi[w2][tid], od = wbd[w2][tid]; u32 op = wbp[w2][tid];
            float a1 = oi*fd, a2 = fi*od;
            if ((a1 > a2) || ((a1==a2) && (op > fp))){ fi=oi; fd=od; fp=op; }
        }
        float r = fi/fd;    // ONE exact IEEE divide per (block,g): ref-exact iou bits
        atomicMax(&best[b*GG+tid], ((u64)__float_as_uint(r)<<32) | (u64)fp);
    }

    double loc_d=0.0, cem_d=0.0;
#pragma unroll
    for (int i=0;i<ITIOU;++i){
        size_t off = (size_t)b*PP + (p0 + i*256);
        mmask[off] = (unsigned short)mm[i];
        if (mm[i]){
            float4 rv = reg[off];
            float pw = px1[i]-px0[i], ph = py1[i]-py0[i];
            float pcx = px0[i]+0.5f*pw, pcy = py0[i]+0.5f*ph;
            float lpw = logf(pw), lph = logf(ph);
            float spn = sp[i] - x[i];
            u32 cb = __float_as_uint(sp[i]) >> 20;
            u32 mmv = mm[i];
            int cntm = 0;
            while (mmv){
                int g = __ffs(mmv) - 1;
                mmv &= mmv - 1u;
                float4 gb = gt[b*GG + g];
                float gw_ = gb.z-gb.x, gh_ = gb.w-gb.y;
                float gcx = gb.x+0.5f*gw_, gcy = gb.y+0.5f*gh_;
                float y0 = (gcx-pcx)/pw;
                float y1 = (gcy-pcy)/ph;
                float y2 = logf(gw_)-lpw;
                float y3 = logf(gh_)-lph;
                float e0=fabsf(y0-rv.x),e1=fabsf(y1-rv.y),e2=fabsf(y2-rv.z),e3=fabsf(y3-rv.w);
                float q0=fminf(e0,1.f),q1=fminf(e1,1.f),q2=fminf(e2,1.f),q3=fminf(e3,1.f);
                float hh=0.5f*(q0*q0+q1*q1+q2*q2+q3*q3)+(e0-q0)+(e1-q1)+(e2-q2)+(e3-q3);
                loc_d += (double)(0.25f*hh);
                ++cntm;
                atomicAdd(&Hm[g*NBIN+cb], 1u);
                atomicAdd(&Sm[g*NBIN+cb], sp[i]);
            }
            cem_d += (double)spn * (double)cntm;
        }
    }
#pragma unroll
    for (int off=32; off>=1; off>>=1){
        loc_d += __shfl_down(loc_d, off);
        cem_d += __shfl_down(cem_d, off);
    }
    if (lane==0){ wl[wv]=loc_d; wc[wv]=cem_d; }
    __syncthreads();
    if (tid==0){
        double L = wl[0]+wl[1]+wl[2]+wl[3];
        double C = wc[0]+wc[1]+wc[2]+wc[3];
        if (L!=0.0) atomicAdd(&scal[0], L);
        if (C!=0.0) atomicAdd(&scal[8], C);
    }
}

// ---- Scan (+argmax fixup prologue): per-g num_pos + threshold bin -----
__global__ __launch_bounds__(256) void k_scan(const float* __restrict__ conf,
                       const float4* __restrict__ reg,
                       const float4* __restrict__ prior,
                       const float4* __restrict__ gt,
                       const u64* __restrict__ best,
                       const u32* __restrict__ sbits,
                       unsigned short* __restrict__ mmask,
                       const u32* __restrict__ Hall, const float* __restrict__ Sall,
                       const u32* __restrict__ Hm, const float* __restrict__ Sm,
                       u32* __restrict__ numpos,
                       u32* __restrict__ Bg, u32* __restrict__ rg, double* __restrict__ sumab,
                       double* __restrict__ scal){
    const int g = blockIdx.x;
    const int t = threadIdx.x;
    __shared__ u32 scs[256];
    __shared__ double svs[256];
    __shared__ u32 smc[256];
    __shared__ int fixbin[BB];
    __shared__ float fixsp[BB];
    __shared__ double fl[BB], fc[BB];
    __shared__ u32 s_nfix;
    // fixup: add the argmax-only matches (<=16 per g)
    if (t < BB){
        fixbin[t] = -1; fixsp[t]=0.f; fl[t]=0.0; fc[t]=0.0;
        u64 k = best[t*GG + g];
        if ((u32)(k >> 32) != 0u){                       // best iou > 0
            u32 bi = 0xFFFFFFFFu - (u32)(k & 0xFFFFFFFFull);
            size_t off = (size_t)t*PP + bi;
            u32* wp = (u32*)(mmask + (off & ~(size_t)1));
            u32 sh = ((u32)off & 1u) * 16u;
            u32 old = atomicOr(wp, ((1u<<g) << sh));
            if (!((old >> sh) & (1u<<g))){               // not already iou>=0.5 matched
                u32 bits = sbits[off];
                float s = __uint_as_float(bits);
                fixbin[t] = (int)(bits >> 20);
                fixsp[t] = s;
                float xv = conf[off];
                fc[t] = (double)(s - xv);
                float4 pb = prior[off];
                float4 gb = gt[t*GG + g];
                float pw = pb.z-pb.x, ph = pb.w-pb.y;
                float pcx = pb.x+0.5f*pw, pcy = pb.y+0.5f*ph;
                float gw_ = gb.z-gb.x, gh_ = gb.w-gb.y;
                float gcx = gb.x+0.5f*gw_, gcy = gb.y+0.5f*gh_;
                float4 rv = reg[off];
                float y0=(gcx-pcx)/pw, y1=(gcy-pcy)/ph;
                float y2=logf(gw_)-logf(pw), y3=logf(gh_)-logf(ph);
                float e0=fabsf(y0-rv.x),e1=fabsf(y1-rv.y),e2=fabsf(y2-rv.z),e3=fabsf(y3-rv.w);
                float q0=fminf(e0,1.f),q1=fminf(e1,1.f),q2=fminf(e2,1.f),q3=fminf(e3,1.f);
                float hh=0.5f*(q0*q0+q1*q1+q2*q2+q3*q3)+(e0-q0)+(e1-q1)+(e2-q2)+(e3-q3);
                fl[t] = (double)(0.25f*hh);
            }
        }
    }
    __syncthreads();
    if (t==0){
        double L=0.0,C=0.0; u32 nf=0u;
        for (int j=0;j<BB;++j){ L+=fl[j]; C+=fc[j]; if (fixbin[j]>=0) ++nf; }
        s_nfix = nf;
        if (L!=0.0) atomicAdd(&scal[0], L);
        if (C!=0.0) atomicAdd(&scal[8], C);
    }
    u32 c[8]; float s8[8];
    u32 cs=0u; double vs=0.0; u32 mc=0u;
#pragma unroll
    for (int i=0;i<8;++i){
        int bin = (NBIN-1) - (t*8+i);
        u32 hm = Hm[g*NBIN+bin];
        u32 ci = Hall[bin] - hm;
        float si = Sall[bin] - Sm[g*NBIN+bin];
        for (int j=0;j<BB;++j){
            if (fixbin[j] == bin){ ci -= 1u; si -= fixsp[j]; }
        }
        c[i]=ci; s8[i]=si; cs += ci; vs += (double)si; mc += hm;
    }
    scs[t]=cs; svs[t]=vs; smc[t]=mc;
    __syncthreads();
    for (int off=128; off>0; off>>=1){
        if (t < off) smc[t] += smc[t+off];
        __syncthreads();
    }
    u32 M = smc[0] + s_nfix;
    if (t==0) numpos[g] = M;
    u32 k = 3u*M;
    if (k == 0u){
        if (t==0){ Bg[g]=0xFFFFFFFFu; rg[g]=0u; sumab[g]=0.0; }
        return;
    }
    for (int off=1; off<256; off<<=1){
        u32 ac = scs[t]; double av = svs[t];
        u32 bc = 0u; double bvv = 0.0;
        if (t>=off){ bc = scs[t-off]; bvv = svs[t-off]; }
        __syncthreads();
        scs[t]=ac+bc; svs[t]=av+bvv;
        __syncthreads();
    }
    u32 cumBase = (t>0)? scs[t-1] : 0u;
    double saBase = (t>0)? svs[t-1] : 0.0;
    if (cumBase < k && scs[t] >= k){
        u32 cum = cumBase; double sa = saBase;
#pragma unroll
        for (int i=0;i<8;++i){
            if (cum + c[i] >= k){
                Bg[g]=(u32)((NBIN-1)-(t*8+i)); rg[g]=k-cum; sumab[g]=sa;
                break;
            }
            cum += c[i]; sa += (double)s8[i];
        }
    }
    if (t==255 && scs[255] < k){   // degenerate fallback (shouldn't happen)
        Bg[g]=0u; rg[g]=1u; sumab[g]=svs[255];
    }
}

// ---- Gather: vectorized uint4 sbits read (4 consecutive priors/lane) ----
__global__ __launch_bounds__(256) void k_gather(const uint4* __restrict__ sbits4,
                                                const unsigned short* __restrict__ mmask,
                                                const u32* __restrict__ Bg,
                                                u32* __restrict__ ccnt,   // padded: g*16
                                                u32* __restrict__ cand, int maxc){
    const int b = blockIdx.x >> 6;
    const int chunk = blockIdx.x & 63;
    const int tid = threadIdx.x;
    __shared__ u32 bg[GG];
    __shared__ u32 cbuf[GG][SLOT];
    __shared__ u32 ccl[GG];
    __shared__ u32 cbase[GG];
    if (tid<GG){ bg[tid]=Bg[tid]; ccl[tid]=0u; }
    __syncthreads();
    // block covers 1024 priors: lane handles 4 consecutive via one 16B load
    uint4 v = sbits4[(size_t)b*(PP/4) + chunk*256 + tid];
    u32 bitsA[4] = {v.x, v.y, v.z, v.w};
    u32 masks[4]; u32 any = 0u;
#pragma unroll
    for (int j=0;j<4;++j){
        u32 cb = bitsA[j]>>20;
        u32 m=0u;
#pragma unroll
        for (int g=0;g<GG;++g) if (bg[g]==cb) m |= (1u<<g);
        masks[j]=m; any |= m;
    }
    if (__ballot(any != 0u) != 0ull){    // wave-uniform skip
        const int pbase = chunk*1024 + tid*4;
#pragma unroll
        for (int j=0;j<4;++j){
            if (masks[j]){
                size_t off = (size_t)b*PP + pbase + j;
                u32 mmv = (u32)mmask[off];
                u32 want = masks[j] & ~mmv;
                while (want){
                    int g = __ffs(want) - 1;
                    want &= want - 1u;
                    u32 idx = atomicAdd(&ccl[g], 1u);
                    if (idx < SLOT) cbuf[g][idx] = bitsA[j];
                    else {       // overflow: direct global (rare, correct)
                        u32 gi = atomicAdd(&ccnt[g*16], 1u);
                        if (gi < (u32)maxc) cand[(size_t)g*(size_t)maxc+gi]=bitsA[j];
                    }
                }
            }
        }
    }
    __syncthreads();
    if (tid < GG){
        u32 cnt = ccl[tid]; if (cnt > SLOT) cnt = SLOT;
        cbase[tid] = cnt ? atomicAdd(&ccnt[tid*16], cnt) : 0u;
        ccl[tid] = cnt;
    }
    __syncthreads();
    for (u32 idx = tid; idx < GG*SLOT; idx += 256u){
        u32 g = idx >> 6;          // SLOT == 64
        u32 j = idx & (SLOT-1u);
        if (j < ccl[g]){
            u32 pos = cbase[g] + j;
            if (pos < (u32)maxc) cand[(size_t)g*(size_t)maxc+pos]=cbuf[g][j];
        }
    }
}

// ---- Select: exact k-th value via 10+10-bit radix; last block writes out ----
__global__ __launch_bounds__(256) void k_select(const u32* __restrict__ Bg, const u32* __restrict__ rg,
                                                const double* __restrict__ sumab,
                                                u32* __restrict__ ccnt, const u32* __restrict__ cand,
                                                int maxc, double* __restrict__ scal,
                                                const u32* __restrict__ numpos,
                                                float* __restrict__ out){
    const int g = blockIdx.x;
    const int tid = threadIdx.x;
    u32 B = Bg[g];
    __shared__ u32 hist[1024];
    __shared__ u32 scs[256];
    __shared__ u32 s_dig, s_rem;
    __shared__ double s_red[4];
    __shared__ u32 s_done;
    if (B != 0xFFFFFFFFu){   // else k==0: no hard negatives, skip to done-tail
        u32 n = ccnt[g*16]; if (n > (u32)maxc) n = (u32)maxc;
        const u32* c = cand + (size_t)g*(size_t)maxc;
        u32 r = rg[g];
        u32 pref = 0u;
#pragma unroll
        for (int round=0; round<2; ++round){
            for (u32 i=tid;i<1024u;i+=256u) hist[i]=0u;
            if (tid==0){ s_dig=0u; s_rem=1u; }
            __syncthreads();
            if (round==0){
                for (u32 i=tid;i<n;i+=256u) atomicAdd(&hist[(c[i]>>10)&1023u],1u);
            } else {
                for (u32 i=tid;i<n;i+=256u){ u32 v=c[i]; if ((v & 0xFFFFFC00u)==pref) atomicAdd(&hist[v&1023u],1u); }
            }
            __syncthreads();
            u32 h[4]; u32 hsum=0u;
#pragma unroll
            for (int i=0;i<4;++i){ h[i]=hist[1023-(tid*4+i)]; hsum+=h[i]; }
            scs[tid]=hsum;
            __syncthreads();
            for (int off=1; off<256; off<<=1){
                u32 a = scs[tid];
                u32 bsum = (tid>=off)? scs[tid-off] : 0u;
                __syncthreads();
                scs[tid]=a+bsum;
                __syncthreads();
            }
            u32 cumBase = (tid>0)? scs[tid-1] : 0u;
            if (cumBase < r && scs[tid] >= r){
                u32 cum = cumBase;
#pragma unroll
                for (int i=0;i<4;++i){
                    if (cum + h[i] >= r){ s_dig = 1023u-(tid*4+i); s_rem = r-cum; break; }
                    cum += h[i];
                }
            }
            __syncthreads();
            if (round==0){
                pref = (B<<20) | (s_dig<<10);
                r = s_rem;
            } else {
                pref = pref | s_dig;
            }
            __syncthreads();
        }
        u32 thr = pref;
        double psum = 0.0;
        for (u32 i=tid;i<n;i+=256u){ u32 v=c[i]; if (v>=thr) psum += (double)__uint_as_float(v); }
#pragma unroll
        for (int off2=32; off2>=1; off2>>=1) psum += __shfl_down(psum, off2);
        if ((tid&63)==0) s_red[tid>>6]=psum;
        __syncthreads();
        if (tid==0){
            double t = s_red[0]+s_red[1]+s_red[2]+s_red[3] + sumab[g];
            atomicAdd(&scal[16], t);
        }
    }
    // ---- fused k_final: last block to finish computes the output ----
    if (tid==0){
        __threadfence();
        s_done = atomicAdd(&ccnt[255], 1u);   // spare zeroed slot as done-counter
    }
    __syncthreads();
    if (tid==0 && s_done == GG-1){
        double L = atomicAdd(&scal[0], 0.0);   // atomic read (coherent)
        double C = atomicAdd(&scal[8], 0.0);
        double S = atomicAdd(&scal[16], 0.0);
        u32 tp=0u;
        for (int gg=0; gg<GG; ++gg) tp += numpos[gg];
        out[0] = (float)((L + C + S) / (double)tp);
    }
}

extern "C" void kernel_launch(void* const* d_in, const int* in_sizes, int n_in,
                              void* d_out, int out_size, void* d_ws, size_t ws_size,
                              hipStream_t stream) {
    const float*  conf  = (const float*) d_in[0];
    const float4* reg   = (const float4*)d_in[1];
    const float4* prior = (const float4*)d_in[2];
    const float4* gt    = (const float4*)d_in[3];
    float* out = (float*)d_out;

    char* ws = (char*)d_ws;
    // workspace layout (bytes)
    u64*    best   = (u64*)   (ws + 0);        // 2048
    u32*    Hall   = (u32*)   (ws + 2048);     // 8192
    float*  Sall   = (float*) (ws + 10240);    // 8192
    u32*    Hm     = (u32*)   (ws + 18432);    // 131072
    float*  Sm     = (float*) (ws + 149504);   // 131072
    double* scal   = (double*)(ws + 280576);   // 3 doubles at 64B stride (idx 0,8,16)
    u32*    ccnt   = (u32*)   (ws + 280832);   // 16 counters padded (+slot 255 = done)
    u32*    Bg     = (u32*)   (ws + 281856);   // 64
    u32*    rg     = (u32*)   (ws + 281920);   // 64
    double* sumab  = (double*)(ws + 281984);   // 128
    u32*    numpos = (u32*)   (ws + 282112);   // 64
    unsigned short* mmask = (unsigned short*)(ws + 282176); // 2097152
    u32*    sbits  = (u32*)   (ws + 2379328);  // 4194304 (16B-aligned)
    const size_t cand_off = 6573632;
    u32*    cand   = (u32*)   (ws + cand_off);

    long long avail = (long long)ws_size - (long long)cand_off;
    int maxc = (avail > 0) ? (int)(avail / (GG*sizeof(u32))) : 0;
    if (maxc > 65536) maxc = 65536;

    dim3 blk(256);
    k_zero  <<<dim3((ZQUADS+255)/256), blk, 0, stream>>>((uint4*)ws, ZQUADS);
    k_hist  <<<dim3(BB*64), blk, 0, stream>>>(conf, sbits, Hall, Sall);
    k_iou   <<<dim3(BB*128), blk, 0, stream>>>(conf, reg, prior, gt, sbits, best, mmask, Hm, Sm, scal);
    k_scan  <<<GG, 256, 0, stream>>>(conf, reg, prior, gt, best, sbits, mmask, Hall, Sall, Hm, Sm, numpos, Bg, rg, sumab, scal);
    k_gather<<<dim3(BB*64), blk, 0, stream>>>((const uint4*)sbits, mmask, Bg, ccnt, cand, maxc);
    k_select<<<GG, 256, 0, stream>>>(Bg, rg, sumab, ccnt, cand, maxc, scal, numpos, out);
}

// Round 12
// 69.870 us; speedup vs baseline: 1.5124x; 1.5124x over previous
//
#include <hip/hip_runtime.h>
#include <math.h>

#define BB 16
#define PP 65536
#define GG 16
#define NBIN 2048
#define ITEMS 4
#define SLOT 64
#define ZBYTES 282176
#define ZQUADS (ZBYTES/16)

typedef unsigned int u32;
typedef unsigned long long u64;

__device__ __forceinline__ float splus(float x){
    float t = __builtin_amdgcn_exp2f(fabsf(x) * -1.4426950408889634f);
    float l = __builtin_amdgcn_logf(1.0f + t);
    return __builtin_fmaf(l, 0.6931471805599453f, fmaxf(x, 0.f));
}

// DPP row-rotate (within 16-lane row) — VALU op, keeps the argmax reduction
// off the DS pipe (shfl_xor = ds_bpermute dep-chains were the round-3 stall).
#define DPP_ROR(v, CTRL) ((u32)__builtin_amdgcn_update_dpp(0, (int)(v), (CTRL), 0xF, 0xF, true))
#define ARG_LEVEL(CTRL) { \
    u32 oiu = DPP_ROR(__float_as_uint(bi_), CTRL); \
    u32 odu = DPP_ROR(__float_as_uint(bd_), CTRL); \
    u32 opu = DPP_ROR(bp_, CTRL); \
    float oi = __uint_as_float(oiu), od = __uint_as_float(odu); \
    float a1 = oi*bd_, a2 = bi_*od; \
    bool take = (a1 > a2) || ((a1 == a2) && (opu > bp_)); \
    if (take){ bi_=oi; bd_=od; bp_=opu; } }

// ---- tiny workspace zero (rocclr small-fill is a ~41us latency-bound kernel) ----
__global__ __launch_bounds__(256) void k_zero(uint4* __restrict__ p, u32 n16){
    u32 i = blockIdx.x*256u + threadIdx.x;
    if (i < n16) p[i] = make_uint4(0u,0u,0u,0u);
}

// ---- k_mb: fused anchor (r10: 40.7us), now 512 threads x 512 blocks:
// same per-thread work (ITEMS=4), half the blocks -> half the NBIN
// zero/flush + Hall/Sall atomic flush + barrier overhead. r11 split showed
// the IoU phase alone costs as much as the fused kernel -> fusion + max
// butterfly amortization is the right structure; occupancy is NOT the lever
// (28-30% at 1KB LDS and at 17KB alike). ----
__global__ __launch_bounds__(512) void k_mb(const float* __restrict__ conf,
                                            const float4* __restrict__ reg,
                                            const float4* __restrict__ prior,
                                            const float4* __restrict__ gt,
                                            u64* __restrict__ best,
                                            unsigned short* __restrict__ mmask,
                                            u32* __restrict__ sbits,
                                            u32* __restrict__ Hall, float* __restrict__ Sall,
                                            u32* __restrict__ Hm, float* __restrict__ Sm,
                                            double* __restrict__ scal){
    const int b = blockIdx.x >> 5;
    const int chunk = blockIdx.x & 31;
    const int tid = threadIdx.x;
    const int lane = tid & 63, wv = tid >> 6;   // wv in [0,8)
    __shared__ u32 hc[NBIN];
    __shared__ float hs[NBIN];
    __shared__ float wbi[8][GG], wbd[8][GG];
    __shared__ u32 wbp[8][GG];
    __shared__ double wl[8], wc[8];
    for (int i=tid;i<NBIN;i+=512){ hc[i]=0u; hs[i]=0.f; }
    __syncthreads();

    const int p0 = chunk*2048 + tid;
    float x[ITEMS], sp[ITEMS];
    float px0[ITEMS], py0[ITEMS], px1[ITEMS], py1[ITEMS], pa[ITEMS];
    u32 invp[ITEMS], mm[ITEMS];
#pragma unroll
    for (int i=0;i<ITEMS;++i){
        int p = p0 + i*512;
        size_t off = (size_t)b*PP + p;
        float xv = conf[off];
        float s = splus(xv);
        x[i]=xv; sp[i]=s; mm[i]=0u;
        invp[i] = 0xFFFFFFFFu - (u32)p;
        u32 bits = __float_as_uint(s);
        sbits[off] = bits;
        u32 cb = bits >> 20;
        atomicAdd(&hc[cb], 1u);
        atomicAdd(&hs[cb], s);
        float4 pb = prior[off];
        px0[i]=pb.x; py0[i]=pb.y; px1[i]=pb.z; py1[i]=pb.w;
        pa[i]=(pb.z-pb.x)*(pb.w-pb.y);
    }

    // exact: RN(inter/den) >= 0.5  <=>  inter/den >= 0.5 - 2^-27 (tie-to-even
    // midpoint rounds UP to 0.5) <=> inter >= (0.5-2^-27)*den, exact in f64.
    const double CH = 0.5 - 1.0/134217728.0;
    const int myg = lane & 15;
    float ti=0.f, td=1.f; u32 tp_=0u;   // this lane's persistent triple for g = myg
#pragma unroll
    for (int g=0; g<GG; ++g){
        float4 gb = gt[b*GG + g];
        float ga = (gb.z-gb.x)*(gb.w-gb.y);
        float bi_ = 0.f, bd_ = 1.f; u32 bp_ = 0u;   // best (inter, den, invp)
#pragma unroll
        for (int i=0;i<ITEMS;++i){
            float lx = fmaxf(px0[i], gb.x), ly = fmaxf(py0[i], gb.y);
            float rx = fminf(px1[i], gb.z), ry = fminf(py1[i], gb.w);
            float w = fmaxf(rx-lx, 0.f), h = fmaxf(ry-ly, 0.f);
            float inter = w*h;                   // boxes <= ~1.05, 100-clip is a no-op
            float den = pa[i] + ga - inter;
            bool pre = (inter >= 0.49f*den);     // conservative; no false negatives
            if (__any(pre)){
                if ((double)inter >= CH*(double)den) mm[i] |= (1u<<g);
            }
            // argmax of inter/den via cross-multiply (division-free)
            float a1 = inter*bd_, a2 = bi_*den;
            bool take = (a1 > a2) || ((a1 == a2) && (invp[i] > bp_));
            if (take){ bi_=inter; bd_=den; bp_=invp[i]; }
        }
        // 4-level VALU (DPP row_ror) reduction within 16-lane groups
        ARG_LEVEL(0x121)   // row_ror:1
        ARG_LEVEL(0x122)   // row_ror:2
        ARG_LEVEL(0x124)   // row_ror:4
        ARG_LEVEL(0x128)   // row_ror:8
        if (myg == g){ ti=bi_; td=bd_; tp_=bp_; }   // keep only own g (static idx)
    }
    // cross-group reduce (4 groups of 16) on the single kept triple: 6 DS ops/wave
#pragma unroll
    for (int off=32; off>=16; off>>=1){
        float oi = __shfl_xor(ti, off);
        float od = __shfl_xor(td, off);
        u32  op = __shfl_xor(tp_, off);
        float a1 = oi*td, a2 = ti*od;
        bool take = (a1 > a2) || ((a1 == a2) && (op > tp_));
        if (take){ ti=oi; td=od; tp_=op; }
    }
    if (lane < 16){ wbi[wv][lane]=ti; wbd[wv][lane]=td; wbp[wv][lane]=tp_; }
    __syncthreads();
    if (tid < GG){
        float fi = wbi[0][tid], fd = wbd[0][tid]; u32 fp = wbp[0][tid];
#pragma unroll
        for (int w2=1; w2<8; ++w2){
            float oi = wbi[w2][tid], od = wbd[w2][tid]; u32 op = wbp[w2][tid];
            float a1 = oi*fd, a2 = fi*od;
            if ((a1 > a2) || ((a1==a2) && (op > fp))){ fi=oi; fd=od; fp=op; }
        }
        float r = fi/fd;    // ONE exact IEEE divide per (block,g): ref-exact iou bits
        atomicMax(&best[b*GG+tid], ((u64)__float_as_uint(r)<<32) | (u64)fp);
    }

    double loc_d=0.0, cem_d=0.0;
#pragma unroll
    for (int i=0;i<ITEMS;++i){
        size_t off = (size_t)b*PP + (p0 + i*512);
        mmask[off] = (unsigned short)mm[i];
        if (mm[i]){
            float4 rv = reg[off];
            float pw = px1[i]-px0[i], ph = py1[i]-py0[i];
            float pcx = px0[i]+0.5f*pw, pcy = py0[i]+0.5f*ph;
            float lpw = logf(pw), lph = logf(ph);
            float spn = sp[i] - x[i];
            u32 cb = __float_as_uint(sp[i]) >> 20;
            u32 mmv = mm[i];
            int cntm = 0;
            while (mmv){
                int g = __ffs(mmv) - 1;
                mmv &= mmv - 1u;
                float4 gb = gt[b*GG + g];
                float gw_ = gb.z-gb.x, gh_ = gb.w-gb.y;
                float gcx = gb.x+0.5f*gw_, gcy = gb.y+0.5f*gh_;
                float y0 = (gcx-pcx)/pw;
                float y1 = (gcy-pcy)/ph;
                float y2 = logf(gw_)-lpw;
                float y3 = logf(gh_)-lph;
                float e0=fabsf(y0-rv.x),e1=fabsf(y1-rv.y),e2=fabsf(y2-rv.z),e3=fabsf(y3-rv.w);
                float q0=fminf(e0,1.f),q1=fminf(e1,1.f),q2=fminf(e2,1.f),q3=fminf(e3,1.f);
                float hh=0.5f*(q0*q0+q1*q1+q2*q2+q3*q3)+(e0-q0)+(e1-q1)+(e2-q2)+(e3-q3);
                loc_d += (double)(0.25f*hh);
                ++cntm;
                atomicAdd(&Hm[g*NBIN+cb], 1u);
                atomicAdd(&Sm[g*NBIN+cb], sp[i]);
            }
            cem_d += (double)spn * (double)cntm;
        }
    }
#pragma unroll
    for (int off=32; off>=1; off>>=1){
        loc_d += __shfl_down(loc_d, off);
        cem_d += __shfl_down(cem_d, off);
    }
    if (lane==0){ wl[wv]=loc_d; wc[wv]=cem_d; }
    __syncthreads();
    if (tid==0){
        double L = 0.0, C = 0.0;
#pragma unroll
        for (int w2=0; w2<8; ++w2){ L += wl[w2]; C += wc[w2]; }
        if (L!=0.0) atomicAdd(&scal[0], L);
        if (C!=0.0) atomicAdd(&scal[8], C);
    }
    __syncthreads();
    for (int i=tid;i<NBIN;i+=512){
        u32 cv = hc[i];
        if (cv){ atomicAdd(&Hall[i], cv); atomicAdd(&Sall[i], hs[i]); }
    }
}

// ---- Scan (+argmax fixup prologue): per-g num_pos + threshold bin -----
__global__ __launch_bounds__(256) void k_scan(const float* __restrict__ conf,
                       const float4* __restrict__ reg,
                       const float4* __restrict__ prior,
                       const float4* __restrict__ gt,
                       const u64* __restrict__ best,
                       const u32* __restrict__ sbits,
                       unsigned short* __restrict__ mmask,
                       const u32* __restrict__ Hall, const float* __restrict__ Sall,
                       const u32* __restrict__ Hm, const float* __restrict__ Sm,
                       u32* __restrict__ numpos,
                       u32* __restrict__ Bg, u32* __restrict__ rg, double* __restrict__ sumab,
                       double* __restrict__ scal){
    const int g = blockIdx.x;
    const int t = threadIdx.x;
    __shared__ u32 scs[256];
    __shared__ double svs[256];
    __shared__ u32 smc[256];
    __shared__ int fixbin[BB];
    __shared__ float fixsp[BB];
    __shared__ double fl[BB], fc[BB];
    __shared__ u32 s_nfix;
    // fixup: add the argmax-only matches (<=16 per g)
    if (t < BB){
        fixbin[t] = -1; fixsp[t]=0.f; fl[t]=0.0; fc[t]=0.0;
        u64 k = best[t*GG + g];
        if ((u32)(k >> 32) != 0u){                       // best iou > 0
            u32 bi = 0xFFFFFFFFu - (u32)(k & 0xFFFFFFFFull);
            size_t off = (size_t)t*PP + bi;
            u32* wp = (u32*)(mmask + (off & ~(size_t)1));
            u32 sh = ((u32)off & 1u) * 16u;
            u32 old = atomicOr(wp, ((1u<<g) << sh));
            if (!((old >> sh) & (1u<<g))){               // not already iou>=0.5 matched
                u32 bits = sbits[off];
                float s = __uint_as_float(bits);
                fixbin[t] = (int)(bits >> 20);
                fixsp[t] = s;
                float xv = conf[off];
                fc[t] = (double)(s - xv);
                float4 pb = prior[off];
                float4 gb = gt[t*GG + g];
                float pw = pb.z-pb.x, ph = pb.w-pb.y;
                float pcx = pb.x+0.5f*pw, pcy = pb.y+0.5f*ph;
                float gw_ = gb.z-gb.x, gh_ = gb.w-gb.y;
                float gcx = gb.x+0.5f*gw_, gcy = gb.y+0.5f*gh_;
                float4 rv = reg[off];
                float y0=(gcx-pcx)/pw, y1=(gcy-pcy)/ph;
                float y2=logf(gw_)-logf(pw), y3=logf(gh_)-logf(ph);
                float e0=fabsf(y0-rv.x),e1=fabsf(y1-rv.y),e2=fabsf(y2-rv.z),e3=fabsf(y3-rv.w);
                float q0=fminf(e0,1.f),q1=fminf(e1,1.f),q2=fminf(e2,1.f),q3=fminf(e3,1.f);
                float hh=0.5f*(q0*q0+q1*q1+q2*q2+q3*q3)+(e0-q0)+(e1-q1)+(e2-q2)+(e3-q3);
                fl[t] = (double)(0.25f*hh);
            }
        }
    }
    __syncthreads();
    if (t==0){
        double L=0.0,C=0.0; u32 nf=0u;
        for (int j=0;j<BB;++j){ L+=fl[j]; C+=fc[j]; if (fixbin[j]>=0) ++nf; }
        s_nfix = nf;
        if (L!=0.0) atomicAdd(&scal[0], L);
        if (C!=0.0) atomicAdd(&scal[8], C);
    }
    u32 c[8]; float s8[8];
    u32 cs=0u; double vs=0.0; u32 mc=0u;
#pragma unroll
    for (int i=0;i<8;++i){
        int bin = (NBIN-1) - (t*8+i);
        u32 hm = Hm[g*NBIN+bin];
        u32 ci = Hall[bin] - hm;
        float si = Sall[bin] - Sm[g*NBIN+bin];
        for (int j=0;j<BB;++j){
            if (fixbin[j] == bin){ ci -= 1u; si -= fixsp[j]; }
        }
        c[i]=ci; s8[i]=si; cs += ci; vs += (double)si; mc += hm;
    }
    scs[t]=cs; svs[t]=vs; smc[t]=mc;
    __syncthreads();
    for (int off=128; off>0; off>>=1){
        if (t < off) smc[t] += smc[t+off];
        __syncthreads();
    }
    u32 M = smc[0] + s_nfix;
    if (t==0) numpos[g] = M;
    u32 k = 3u*M;
    if (k == 0u){
        if (t==0){ Bg[g]=0xFFFFFFFFu; rg[g]=0u; sumab[g]=0.0; }
        return;
    }
    for (int off=1; off<256; off<<=1){
        u32 ac = scs[t]; double av = svs[t];
        u32 bc = 0u; double bvv = 0.0;
        if (t>=off){ bc = scs[t-off]; bvv = svs[t-off]; }
        __syncthreads();
        scs[t]=ac+bc; svs[t]=av+bvv;
        __syncthreads();
    }
    u32 cumBase = (t>0)? scs[t-1] : 0u;
    double saBase = (t>0)? svs[t-1] : 0.0;
    if (cumBase < k && scs[t] >= k){
        u32 cum = cumBase; double sa = saBase;
#pragma unroll
        for (int i=0;i<8;++i){
            if (cum + c[i] >= k){
                Bg[g]=(u32)((NBIN-1)-(t*8+i)); rg[g]=k-cum; sumab[g]=sa;
                break;
            }
            cum += c[i]; sa += (double)s8[i];
        }
    }
    if (t==255 && scs[255] < k){   // degenerate fallback (shouldn't happen)
        Bg[g]=0u; rg[g]=1u; sumab[g]=svs[255];
    }
}

// ---- Gather: vectorized uint4 sbits read (4 consecutive priors/lane) ----
__global__ __launch_bounds__(256) void k_gather(const uint4* __restrict__ sbits4,
                                                const unsigned short* __restrict__ mmask,
                                                const u32* __restrict__ Bg,
                                                u32* __restrict__ ccnt,   // padded: g*16
                                                u32* __restrict__ cand, int maxc){
    const int b = blockIdx.x >> 6;
    const int chunk = blockIdx.x & 63;
    const int tid = threadIdx.x;
    __shared__ u32 bg[GG];
    __shared__ u32 cbuf[GG][SLOT];
    __shared__ u32 ccl[GG];
    __shared__ u32 cbase[GG];
    if (tid<GG){ bg[tid]=Bg[tid]; ccl[tid]=0u; }
    __syncthreads();
    // block covers 1024 priors: lane handles 4 consecutive via one 16B load
    uint4 v = sbits4[(size_t)b*(PP/4) + chunk*256 + tid];
    u32 bitsA[4] = {v.x, v.y, v.z, v.w};
    u32 masks[4]; u32 any = 0u;
#pragma unroll
    for (int j=0;j<4;++j){
        u32 cb = bitsA[j]>>20;
        u32 m=0u;
#pragma unroll
        for (int g=0;g<GG;++g) if (bg[g]==cb) m |= (1u<<g);
        masks[j]=m; any |= m;
    }
    if (__ballot(any != 0u) != 0ull){    // wave-uniform skip
        const int pbase = chunk*1024 + tid*4;
#pragma unroll
        for (int j=0;j<4;++j){
            if (masks[j]){
                size_t off = (size_t)b*PP + pbase + j;
                u32 mmv = (u32)mmask[off];
                u32 want = masks[j] & ~mmv;
                while (want){
                    int g = __ffs(want) - 1;
                    want &= want - 1u;
                    u32 idx = atomicAdd(&ccl[g], 1u);
                    if (idx < SLOT) cbuf[g][idx] = bitsA[j];
                    else {       // overflow: direct global (rare, correct)
                        u32 gi = atomicAdd(&ccnt[g*16], 1u);
                        if (gi < (u32)maxc) cand[(size_t)g*(size_t)maxc+gi]=bitsA[j];
                    }
                }
            }
        }
    }
    __syncthreads();
    if (tid < GG){
        u32 cnt = ccl[tid]; if (cnt > SLOT) cnt = SLOT;
        cbase[tid] = cnt ? atomicAdd(&ccnt[tid*16], cnt) : 0u;
        ccl[tid] = cnt;
    }
    __syncthreads();
    for (u32 idx = tid; idx < GG*SLOT; idx += 256u){
        u32 g = idx >> 6;          // SLOT == 64
        u32 j = idx & (SLOT-1u);
        if (j < ccl[g]){
            u32 pos = cbase[g] + j;
            if (pos < (u32)maxc) cand[(size_t)g*(size_t)maxc+pos]=cbuf[g][j];
        }
    }
}

// ---- Select: exact k-th value via 10+10-bit radix; last block writes out ----
__global__ __launch_bounds__(256) void k_select(const u32* __restrict__ Bg, const u32* __restrict__ rg,
                                                const double* __restrict__ sumab,
                                                u32* __restrict__ ccnt, const u32* __restrict__ cand,
                                                int maxc, double* __restrict__ scal,
                                                const u32* __restrict__ numpos,
                                                float* __restrict__ out){
    const int g = blockIdx.x;
    const int tid = threadIdx.x;
    u32 B = Bg[g];
    __shared__ u32 hist[1024];
    __shared__ u32 scs[256];
    __shared__ u32 s_dig, s_rem;
    __shared__ double s_red[4];
    __shared__ u32 s_done;
    if (B != 0xFFFFFFFFu){   // else k==0: no hard negatives, skip to done-tail
        u32 n = ccnt[g*16]; if (n > (u32)maxc) n = (u32)maxc;
        const u32* c = cand + (size_t)g*(size_t)maxc;
        u32 r = rg[g];
        u32 pref = 0u;
#pragma unroll
        for (int round=0; round<2; ++round){
            for (u32 i=tid;i<1024u;i+=256u) hist[i]=0u;
            if (tid==0){ s_dig=0u; s_rem=1u; }
            __syncthreads();
            if (round==0){
                for (u32 i=tid;i<n;i+=256u) atomicAdd(&hist[(c[i]>>10)&1023u],1u);
            } else {
                for (u32 i=tid;i<n;i+=256u){ u32 v=c[i]; if ((v & 0xFFFFFC00u)==pref) atomicAdd(&hist[v&1023u],1u); }
            }
            __syncthreads();
            u32 h[4]; u32 hsum=0u;
#pragma unroll
            for (int i=0;i<4;++i){ h[i]=hist[1023-(tid*4+i)]; hsum+=h[i]; }
            scs[tid]=hsum;
            __syncthreads();
            for (int off=1; off<256; off<<=1){
                u32 a = scs[tid];
                u32 bsum = (tid>=off)? scs[tid-off] : 0u;
                __syncthreads();
                scs[tid]=a+bsum;
                __syncthreads();
            }
            u32 cumBase = (tid>0)? scs[tid-1] : 0u;
            if (cumBase < r && scs[tid] >= r){
                u32 cum = cumBase;
#pragma unroll
                for (int i=0;i<4;++i){
                    if (cum + h[i] >= r){ s_dig = 1023u-(tid*4+i); s_rem = r-cum; break; }
                    cum += h[i];
                }
            }
            __syncthreads();
            if (round==0){
                pref = (B<<20) | (s_dig<<10);
                r = s_rem;
            } else {
                pref = pref | s_dig;
            }
            __syncthreads();
        }
        u32 thr = pref;
        double psum = 0.0;
        for (u32 i=tid;i<n;i+=256u){ u32 v=c[i]; if (v>=thr) psum += (double)__uint_as_float(v); }
#pragma unroll
        for (int off2=32; off2>=1; off2>>=1) psum += __shfl_down(psum, off2);
        if ((tid&63)==0) s_red[tid>>6]=psum;
        __syncthreads();
        if (tid==0){
            double t = s_red[0]+s_red[1]+s_red[2]+s_red[3] + sumab[g];
            atomicAdd(&scal[16], t);
        }
    }
    // ---- fused k_final: last block to finish computes the output ----
    if (tid==0){
        __threadfence();
        s_done = atomicAdd(&ccnt[255], 1u);   // spare zeroed slot as done-counter
    }
    __syncthreads();
    if (tid==0 && s_done == GG-1){
        double L = atomicAdd(&scal[0], 0.0);   // atomic read (coherent)
        double C = atomicAdd(&scal[8], 0.0);
        double S = atomicAdd(&scal[16], 0.0);
        u32 tp=0u;
        for (int gg=0; gg<GG; ++gg) tp += numpos[gg];
        out[0] = (float)((L + C + S) / (double)tp);
    }
}

extern "C" void kernel_launch(void* const* d_in, const int* in_sizes, int n_in,
                              void* d_out, int out_size, void* d_ws, size_t ws_size,
                              hipStream_t stream) {
    const float*  conf  = (const float*) d_in[0];
    const float4* reg   = (const float4*)d_in[1];
    const float4* prior = (const float4*)d_in[2];
    const float4* gt    = (const float4*)d_in[3];
    float* out = (float*)d_out;

    char* ws = (char*)d_ws;
    // workspace layout (bytes)
    u64*    best   = (u64*)   (ws + 0);        // 2048
    u32*    Hall   = (u32*)   (ws + 2048);     // 8192
    float*  Sall   = (float*) (ws + 10240);    // 8192
    u32*    Hm     = (u32*)   (ws + 18432);    // 131072
    float*  Sm     = (float*) (ws + 149504);   // 131072
    double* scal   = (double*)(ws + 280576);   // 3 doubles at 64B stride (idx 0,8,16)
    u32*    ccnt   = (u32*)   (ws + 280832);   // 16 counters padded (+slot 255 = done)
    u32*    Bg     = (u32*)   (ws + 281856);   // 64
    u32*    rg     = (u32*)   (ws + 281920);   // 64
    double* sumab  = (double*)(ws + 281984);   // 128
    u32*    numpos = (u32*)   (ws + 282112);   // 64
    unsigned short* mmask = (unsigned short*)(ws + 282176); // 2097152
    u32*    sbits  = (u32*)   (ws + 2379328);  // 4194304 (16B-aligned)
    const size_t cand_off = 6573632;
    u32*    cand   = (u32*)   (ws + cand_off);

    long long avail = (long long)ws_size - (long long)cand_off;
    int maxc = (avail > 0) ? (int)(avail / (GG*sizeof(u32))) : 0;
    if (maxc > 65536) maxc = 65536;

    dim3 blk(256);
    k_zero  <<<dim3((ZQUADS+255)/256), blk, 0, stream>>>((uint4*)ws, ZQUADS);
    k_mb    <<<dim3(BB*32), dim3(512), 0, stream>>>(conf, reg, prior, gt, best, mmask, sbits, Hall, Sall, Hm, Sm, scal);
    k_scan  <<<GG, 256, 0, stream>>>(conf, reg, prior, gt, best, sbits, mmask, Hall, Sall, Hm, Sm, numpos, Bg, rg, sumab, scal);
    k_gather<<<dim3(BB*64), blk, 0, stream>>>((const uint4*)sbits, mmask, Bg, ccnt, cand, maxc);
    k_select<<<GG, 256, 0, stream>>>(Bg, rg, sumab, ccnt, cand, maxc, scal, numpos, out);
}